// Round 8
// baseline (242.245 us; speedup 1.0000x reference)
//
#include <hip/hip_runtime.h>
#include <hip/hip_fp16.h>
#include <stdint.h>

typedef float floatx4 __attribute__((ext_vector_type(4)));
typedef short short8 __attribute__((ext_vector_type(8)));

constexpr int I_SZ = 256, O_SZ = 256, NCOL = 512, B_SZ = 4096;
constexpr int KSTEPS = 264;           // 256 RBF steps + 8 silu steps
constexpr float GSTEP = 4.0f / 7.0f;  // linspace(-2,2,8) step
constexpr float NLOG2E = -1.44269504088896f;

// pack two fp32 -> two bf16 (truncate) in one v_perm_b32
__device__ __forceinline__ uint32_t pk_bf16(float lo, float hi) {
  return __builtin_amdgcn_perm(__float_as_uint(hi), __float_as_uint(lo), 0x07060302u);
}
__device__ __forceinline__ short rne_bf16(float f) {
  uint32_t u = __float_as_uint(f);
  return (short)((u + 0x7FFFu + ((u >> 16) & 1u)) >> 16);
}

__device__ __forceinline__ void gload_lds16(const void* g, void* l) {
  __builtin_amdgcn_global_load_lds((const __attribute__((address_space(1))) void*)g,
                                   (__attribute__((address_space(3))) void*)l,
                                   16, 0, 0);
}

__device__ __forceinline__ float silu_f(float a) {
  return a * __builtin_amdgcn_rcpf(1.f + __builtin_amdgcn_exp2f(a * NLOG2E));
}

// R5-R7 BUG FIX: __half_raw::data is _Float16 (VALUE member) in HIP — assigning a ushort to it
// converts arithmetically (15432 -> 15432.0f16), corrupting every prefetched x. Bit-exact
// reinterpret via memcpy instead (compiles to a plain mov).
__device__ __forceinline__ float h2f_raw(unsigned short u) {
  _Float16 h;
  __builtin_memcpy(&h, &u, 2);
  return (float)h;
}

// ---------------- weight packing: K-major Wpack[s][ph][slot][n][e] bf16, u = ph*4+slot ----------------
// (verbatim from round 3, harness-verified)
__global__ void pack_weights(const float* __restrict__ rw, const float* __restrict__ cw,
                             const float* __restrict__ swre, const float* __restrict__ swim,
                             short* __restrict__ wpack) {
  int idx = blockIdx.x * 256 + threadIdx.x;   // (s, ph, slot, n): 264*2*4*512 groups of 8
  int n = idx & 511;
  int slot = (idx >> 9) & 3;
  int ph = (idx >> 11) & 1;
  int s = idx >> 12;
  int u = ph * 4 + slot;                      // k-group: k = u*8 + e
  int o = n >> 1, c = n & 1;
  float w[8];
  if (s < 256) {
    const float* W = (c ? cw : rw) + (((size_t)s * O_SZ + o) << 6) + (u << 3);
    float4 a = *(const float4*)W;
    float4 b = *(const float4*)(W + 4);
    w[0] = a.x; w[1] = a.y; w[2] = a.z; w[3] = a.w;
    w[4] = b.x; w[5] = b.y; w[6] = b.z; w[7] = b.w;
  } else {
    int kp0 = ((s - 256) << 6) + (u << 3);
    #pragma unroll
    for (int e = 0; e < 8; ++e) {
      int kp = kp0 + e, i = kp >> 1, ci = kp & 1;
      float a = swre[i * O_SZ + o], b = swim[i * O_SZ + o];
      w[e] = (c == 0) ? (ci == 0 ? a : -b) : (ci == 0 ? b : a);
    }
  }
  uint32_t h[8];
  #pragma unroll
  for (int e = 0; e < 8; ++e) h[e] = (uint32_t)(uint16_t)rne_bf16(w[e]);
  uint4 val = make_uint4(h[0] | (h[1] << 16), h[2] | (h[3] << 16),
                         h[4] | (h[5] << 16), h[6] | (h[7] << 16));
  *(uint4*)(wpack + (size_t)idx * 8) = val;
}

// ---------------- x transpose: xT[c][i][b] fp16 from x[b][i] fp32 ----------------
__global__ void transpose_x(const float* __restrict__ xre, const float* __restrict__ xim,
                            __half* __restrict__ xT) {
  __shared__ float tile[64][65];
  int bt = blockIdx.x & 63;
  int it = (blockIdx.x >> 6) & 3;
  int c  = blockIdx.x >> 8;
  const float* src = (c ? xim : xre);
  int b0 = bt << 6, i0 = it << 6;
  int t = threadIdx.x;
  int il = t & 63, bh = t >> 6;
  #pragma unroll
  for (int k = 0; k < 16; ++k) {
    int bl = bh + (k << 2);
    tile[bl][il] = src[(size_t)(b0 + bl) * I_SZ + i0 + il];
  }
  __syncthreads();
  int bl2 = t & 63, ih = t >> 6;
  __half* dst = xT + ((size_t)c * I_SZ + i0) * B_SZ + b0;
  #pragma unroll
  for (int k = 0; k < 16; ++k) {
    int il2 = ih + (k << 2);
    dst[(size_t)il2 * B_SZ + bl2] = __float2half(tile[bl2][il2]);
  }
}

// ---------------- bias column sums ----------------
__global__ void bias_sums(const float* __restrict__ bre, const float* __restrict__ bim,
                          float* __restrict__ bsum) {
  int n = blockIdx.x, o = n >> 1, l = threadIdx.x;
  const float* src = ((n & 1) ? bim : bre) + o;
  float s = 0.f;
  #pragma unroll
  for (int a = 0; a < 4; ++a) s += src[(size_t)(a * 64 + l) * O_SZ];
  #pragma unroll
  for (int off = 32; off; off >>= 1) s += __shfl_down(s, off, 64);
  if (l == 0) bsum[n] = s;
}

// ---------------- main fused GEMM ----------------
// Round-0 verified skeleton (128x128 tile, 4 waves/256 thr, 2 barriers/step, grid 1024 = 4/CU,
// kch = bid&7 XCD-aligned), with the measured serial chain shortened:
//  - K=32 half-steps (66 steps) using round-3's verified K-major pack + fragment mapping
//  - B double-buffered (2x8 KB); stage of B(t+1) issued at TOP of step t -> its vmcnt(0)
//    drain (before the publish barrier) sits ~500+ cyc after issue: ~zero exposed latency
//  - x prefetched one s ahead into 2 raw ushorts -> x-wait leaves the serial region
//  - A single-buffered 8 KB, built between the two barriers (reads done / publish)
// LDS 24 KB, regs pinned <=64 VGPR (+64 acc) by launch_bounds(256,4) -> 4 blocks/CU.
__global__ __launch_bounds__(256, 4) void cvkan_gemm(
    const float* __restrict__ xre, const float* __restrict__ xim,
    const __half* __restrict__ xT,
    const short* __restrict__ wpack, const float* __restrict__ bsum,
    float* __restrict__ out) {
  __shared__ __align__(16) short As[4 * 128 * 8];      // [slot][row][8]      8 KB
  __shared__ __align__(16) short Bs[2][4 * 128 * 8];   // dbuf [slot][col][8] 2x8 KB

  const int tid = threadIdx.x;
  const int bid = blockIdx.x;
  const int kch = bid & 7;              // XCD-aligned: ~2MB wpack slice per XCD L2
  const int mn = bid >> 3;
  const int mt = mn >> 2, nt = mn & 3;
  const int b0 = mt * 128, n0 = nt * 128;
  const int l = tid & 63, w = tid >> 6;
  const int wr = w >> 1, wc = w & 1;    // 2x2 wave grid, each wave 64x64
  const int lm = l & 15, q = l >> 4;
  const int r = tid >> 1, h = tid & 1;  // A-build: row r (0..127), half h (2 k-slots each)

  const __half* xTre = xT;
  const __half* xTim = xT + (size_t)I_SZ * B_SZ;

  floatx4 acc[4][4] = {};

  // half-step t (0..65): js = t>>1, ph = t&1; s = js<32 ? kch*32+js : 256+kch
  auto stage_B = [&](short* bdst, int t) {
    int js = t >> 1, ph = t & 1;
    int s = (js < 32) ? (kch * 32 + js) : (256 + kch);
    const short* src = wpack + (size_t)s * 32768 + (size_t)ph * 16384
                       + ((tid >> 7) << 12) + ((size_t)(n0 + (tid & 127)) << 3);
    short* ldst = bdst + (w << 9);      // wave-uniform base; HW adds lane*16B -> LDS off = tid*8
    gload_lds16(src,        ldst);      // slots 0,1
    gload_lds16(src + 8192, ldst + 2048);  // slots 2,3
  };

  // build this thread's 2 k-slots of A for half-step (ph', s'): slots u_loc = h*2+{0,1}
  auto build_rbf = [&](int phn, float xr, float xi) {
    float eiv[8];
    #pragma unroll
    for (int v = 0; v < 8; ++v) {
      float d = xi - (-2.0f + v * GSTEP);
      eiv[v] = __builtin_amdgcn_exp2f(d * d * NLOG2E);
    }
    #pragma unroll
    for (int j = 0; j < 2; ++j) {
      int u_loc = h * 2 + j;
      int u = phn * 4 + u_loc;
      float d = xr - (-2.0f + u * GSTEP);
      float er = __builtin_amdgcn_exp2f(d * d * NLOG2E);
      uint4 val = make_uint4(pk_bf16(er * eiv[0], er * eiv[1]), pk_bf16(er * eiv[2], er * eiv[3]),
                             pk_bf16(er * eiv[4], er * eiv[5]), pk_bf16(er * eiv[6], er * eiv[7]));
      *(uint4*)(As + u_loc * 1024 + r * 8) = val;
    }
  };

  // silu half-step: k = u*8+e -> i = kch*32 + u*4 + (e>>1), plane = e&1 (pack-verified mapping)
  auto build_silu = [&](int phn) {
    #pragma unroll
    for (int j = 0; j < 2; ++j) {
      int u_loc = h * 2 + j;
      int u = phn * 4 + u_loc;
      const float* pr = xre + (size_t)(b0 + r) * I_SZ + (kch << 5) + (u << 2);
      const float* pi = xim + (size_t)(b0 + r) * I_SZ + (kch << 5) + (u << 2);
      uint4 val = make_uint4(pk_bf16(silu_f(pr[0]), silu_f(pi[0])),
                             pk_bf16(silu_f(pr[1]), silu_f(pi[1])),
                             pk_bf16(silu_f(pr[2]), silu_f(pi[2])),
                             pk_bf16(silu_f(pr[3]), silu_f(pi[3])));
      *(uint4*)(As + u_loc * 1024 + r * 8) = val;
    }
  };

  // ---- prologue: x(s0) -> build A(0) (ph=0); stage B(0); drain; publish ----
  float xr_s, xi_s;
  {
    int s0 = kch * 32;
    xr_s = __half2float(xTre[(size_t)s0 * B_SZ + b0 + r]);
    xi_s = __half2float(xTim[(size_t)s0 * B_SZ + b0 + r]);
    stage_B(&Bs[0][0], 0);
    build_rbf(0, xr_s, xi_s);
    asm volatile("s_waitcnt vmcnt(0) lgkmcnt(0)" ::: "memory");
  }
  __syncthreads();

  unsigned short hxr_n = 0, hxi_n = 0;   // raw fp16 x for the next s (issued at odd t)

  for (int t = 0; t < 66; ++t) {
    // issue next-s x loads early (consumed in this step's build phase)
    if (t < 65 && (t & 1)) {
      int jn = (t + 1) >> 1;
      if (jn < 32) {
        int sn = kch * 32 + jn;
        hxr_n = *(const unsigned short*)&xTre[(size_t)sn * B_SZ + b0 + r];
        hxi_n = *(const unsigned short*)&xTim[(size_t)sn * B_SZ + b0 + r];
      }
    }
    // stage B(t+1) into the idle dbuf half; drains ~500+ cyc later (frag+MFMA+build cover)
    if (t < 65) stage_B(&Bs[(t + 1) & 1][0], t + 1);
    __builtin_amdgcn_sched_barrier(0);   // keep the issues above the compute below

    // ---- fragments (K-major, round-3-verified mapping) + 16 MFMA ----
    const short* bb = &Bs[t & 1][0];
    short8 bf[4];
    #pragma unroll
    for (int nn = 0; nn < 4; ++nn)
      bf[nn] = *(const short8*)(bb + q * 1024 + (wc * 64 + nn * 16 + lm) * 8);
    __builtin_amdgcn_s_setprio(1);
    #pragma unroll
    for (int mm = 0; mm < 4; ++mm) {
      short8 a = *(const short8*)(As + q * 1024 + (wr * 64 + mm * 16 + lm) * 8);
      #pragma unroll
      for (int nn = 0; nn < 4; ++nn)
        acc[mm][nn] = __builtin_amdgcn_mfma_f32_16x16x32_bf16(a, bf[nn], acc[mm][nn], 0, 0, 0);
    }
    __builtin_amdgcn_s_setprio(0);

    if (t < 65) {
      __syncthreads();                   // all reads of As & Bs[t&1] complete
      // build A(t+1) between the barriers (serial region: ~10 exp2 + 2 ds_write)
      int tn = t + 1, jn = tn >> 1, phn = tn & 1;
      if (jn >= 32) {
        build_silu(phn);
      } else {
        if (phn == 0) { xr_s = h2f_raw(hxr_n); xi_s = h2f_raw(hxi_n); }  // new s at even t+1
        build_rbf(phn, xr_s, xi_s);
      }
      // publish: A ds_writes (lgkm) + B(t+1) stage (vmcnt, issued at top of this step)
      asm volatile("s_waitcnt vmcnt(0) lgkmcnt(0)" ::: "memory");
      __syncthreads();
    }
  }

  // ---- epilogue: C/D layout col=lane&15, row=q*4+reg; bias added by chunk-7 only ----
  #pragma unroll
  for (int nn = 0; nn < 4; ++nn) {
    int col = n0 + wc * 64 + nn * 16 + lm;
    float bv = (kch == 7) ? bsum[col] : 0.0f;
    #pragma unroll
    for (int mm = 0; mm < 4; ++mm) {
      int row0 = b0 + wr * 64 + mm * 16 + (q << 2);
      #pragma unroll
      for (int r2 = 0; r2 < 4; ++r2)
        atomicAdd(out + (size_t)(row0 + r2) * NCOL + col, acc[mm][nn][r2] + bv);
    }
  }
}

extern "C" void kernel_launch(void* const* d_in, const int* in_sizes, int n_in,
                              void* d_out, int out_size, void* d_ws, size_t ws_size,
                              hipStream_t stream) {
  const float* xre  = (const float*)d_in[0];
  const float* xim  = (const float*)d_in[1];
  const float* rw   = (const float*)d_in[2];
  const float* cw   = (const float*)d_in[3];
  const float* swre = (const float*)d_in[4];
  const float* swim = (const float*)d_in[5];
  const float* bre  = (const float*)d_in[6];
  const float* bim  = (const float*)d_in[7];
  float* out = (float*)d_out;

  size_t wpack_bytes = (size_t)KSTEPS * NCOL * 64 * 2;   // 16.5 MiB
  short* wpack = (short*)d_ws;
  float* bsum  = (float*)((char*)d_ws + wpack_bytes);
  __half* xT   = (__half*)((char*)d_ws + wpack_bytes + 2048);  // 2 planes * 256*4096 fp16

  hipMemsetAsync(d_out, 0, (size_t)B_SZ * NCOL * sizeof(float), stream);
  pack_weights<<<(KSTEPS * NCOL * 8) / 256, 256, 0, stream>>>(rw, cw, swre, swim, wpack);
  transpose_x<<<512, 256, 0, stream>>>(xre, xim, xT);
  bias_sums<<<NCOL, 64, 0, stream>>>(bre, bim, bsum);
  cvkan_gemm<<<1024, 256, 0, stream>>>(xre, xim, xT, wpack, bsum, out);
}

// Round 9
// 220.997 us; speedup vs baseline: 1.0961x; 1.0961x over previous
//
#include <hip/hip_runtime.h>
#include <hip/hip_fp16.h>
#include <stdint.h>

typedef float floatx4 __attribute__((ext_vector_type(4)));
typedef short short8 __attribute__((ext_vector_type(8)));

constexpr int I_SZ = 256, O_SZ = 256, NCOL = 512, B_SZ = 4096;
constexpr int KSTEPS = 264;           // 256 RBF steps + 8 silu steps
constexpr float GSTEP = 4.0f / 7.0f;  // linspace(-2,2,8) step
constexpr float NLOG2E = -1.44269504088896f;

// pack two fp32 -> two bf16 (truncate) in one v_perm_b32
__device__ __forceinline__ uint32_t pk_bf16(float lo, float hi) {
  return __builtin_amdgcn_perm(__float_as_uint(hi), __float_as_uint(lo), 0x07060302u);
}
__device__ __forceinline__ short rne_bf16(float f) {
  uint32_t u = __float_as_uint(f);
  return (short)((u + 0x7FFFu + ((u >> 16) & 1u)) >> 16);
}

__device__ __forceinline__ void gload_lds16(const void* g, void* l) {
  __builtin_amdgcn_global_load_lds((const __attribute__((address_space(1))) void*)g,
                                   (__attribute__((address_space(3))) void*)l,
                                   16, 0, 0);
}

__device__ __forceinline__ float silu_f(float a) {
  return a * __builtin_amdgcn_rcpf(1.f + __builtin_amdgcn_exp2f(a * NLOG2E));
}

// ---------------- weight packing (VERBATIM round-0, harness-verified):
// Wpack[kb][n][gp][e] bf16, gp = g ^ (n&7); zero-bank-conflict read layout ----------------
__global__ void pack_weights(const float* __restrict__ rw, const float* __restrict__ cw,
                             const float* __restrict__ swre, const float* __restrict__ swim,
                             short* __restrict__ wpack) {
  int idx = blockIdx.x * 256 + threadIdx.x;   // enumerates (kb, n, gp): 264*512*8
  int kb = idx >> 12;
  int rem = idx & 4095;
  int n = rem >> 3, gp = rem & 7;
  int g = gp ^ (n & 7);
  int o = n >> 1, c = n & 1;
  float w[8];
  if (kb < 256) {
    const float* W = (c ? cw : rw) + (((size_t)kb * O_SZ + o) << 6) + (g << 3);
    float4 a = *(const float4*)W;
    float4 b = *(const float4*)(W + 4);
    w[0] = a.x; w[1] = a.y; w[2] = a.z; w[3] = a.w;
    w[4] = b.x; w[5] = b.y; w[6] = b.z; w[7] = b.w;
  } else {
    int kp0 = ((kb - 256) << 6) + (g << 3);
    #pragma unroll
    for (int e = 0; e < 8; ++e) {
      int kp = kp0 + e, i = kp >> 1, ci = kp & 1;
      float a = swre[i * O_SZ + o], b = swim[i * O_SZ + o];
      w[e] = (c == 0) ? (ci == 0 ? a : -b) : (ci == 0 ? b : a);
    }
  }
  uint32_t h[8];
  #pragma unroll
  for (int e = 0; e < 8; ++e) h[e] = (uint32_t)(uint16_t)rne_bf16(w[e]);
  uint4 val = make_uint4(h[0] | (h[1] << 16), h[2] | (h[3] << 16),
                         h[4] | (h[5] << 16), h[6] | (h[7] << 16));
  *(uint4*)(wpack + (size_t)idx * 8) = val;
}

// ---------------- x transpose: xT[c][i][b] fp16 from x[b][i] fp32 (verbatim, verified) ----------------
__global__ void transpose_x(const float* __restrict__ xre, const float* __restrict__ xim,
                            __half* __restrict__ xT) {
  __shared__ float tile[64][65];
  int bt = blockIdx.x & 63;
  int it = (blockIdx.x >> 6) & 3;
  int c  = blockIdx.x >> 8;
  const float* src = (c ? xim : xre);
  int b0 = bt << 6, i0 = it << 6;
  int t = threadIdx.x;
  int il = t & 63, bh = t >> 6;
  #pragma unroll
  for (int k = 0; k < 16; ++k) {
    int bl = bh + (k << 2);
    tile[bl][il] = src[(size_t)(b0 + bl) * I_SZ + i0 + il];
  }
  __syncthreads();
  int bl2 = t & 63, ih = t >> 6;
  __half* dst = xT + ((size_t)c * I_SZ + i0) * B_SZ + b0;
  #pragma unroll
  for (int k = 0; k < 16; ++k) {
    int il2 = ih + (k << 2);
    dst[(size_t)il2 * B_SZ + bl2] = __float2half(tile[bl2][il2]);
  }
}

// ---------------- bias column sums (verbatim, verified) ----------------
__global__ void bias_sums(const float* __restrict__ bre, const float* __restrict__ bim,
                          float* __restrict__ bsum) {
  int n = blockIdx.x, o = n >> 1, l = threadIdx.x;
  const float* src = ((n & 1) ? bim : bre) + o;
  float s = 0.f;
  #pragma unroll
  for (int a = 0; a < 4; ++a) s += src[(size_t)(a * 64 + l) * O_SZ];
  #pragma unroll
  for (int off = 32; off; off >>= 1) s += __shfl_down(s, off, 64);
  if (l == 0) bsum[n] = s;
}

// ---------------- main fused GEMM: A in registers, B-only LDS ----------------
// The A-fragment for mfma(A,B) (row=lane&15, k=(lane>>4)*8+e — the mapping R0's verified LDS
// path implements) is per-lane computable: lane (lm,q) needs er(xr[row],g_q)*eiv[e]. So A never
// touches LDS: no A-barrier, no A bank behavior, build overlaps MFMA in the same wave.
// Wave = 64x128 out (4 row-tiles x 8 col-tiles, acc 128 AGPR); block = 4 waves = 128x256 tile.
// Grid = 32 mt x 2 nt x 8 kch = 512 = exactly 2 blocks/CU; kch = bid&7 XCD-aligned.
// B: R0's verified swizzled layout [col][gp][e] (0 conflicts), K=64/step, dbuf 2x32 KB,
// ONE barrier/step (stage t+1 at step top -> vmcnt(0) free by barrier time).
__global__ __launch_bounds__(256, 2) void cvkan_gemm(
    const float* __restrict__ xre, const float* __restrict__ xim,
    const __half* __restrict__ xT,
    const short* __restrict__ wpack, const float* __restrict__ bsum,
    float* __restrict__ out) {
  __shared__ __align__(16) short Bs[2][256 * 64];   // dbuf [col 0..255][gp][e], 2x32 KB

  const int tid = threadIdx.x;
  const int bid = blockIdx.x;
  const int kch = bid & 7;              // XCD-aligned: ~2.1 MB wpack slice per XCD L2
  const int mn = bid >> 3;
  const int mt = mn >> 1, nt = mn & 1;
  const int b0 = mt * 128, n0 = nt * 256;
  const int l = tid & 63, w = tid >> 6;
  const int wr = w >> 1, wc = w & 1;    // 2x2 wave grid: rows wr*64, cols wc*128
  const int lm = l & 15, q = l >> 4;
  const float gq  = -2.0f + q * GSTEP;  // RBF grid point for u = q
  const float gq4 = gq + 4.0f * GSTEP;  // u = q+4

  const __half* xTre = xT;
  const __half* xTim = xT + (size_t)I_SZ * B_SZ;

  floatx4 acc[4][8] = {};               // [row-tile][col-tile], 128 AGPR

  // stage one 32 KB B tile (256 cols x 64 k, swizzled layout is linear copy):
  auto stage_B = [&](short* bdst, int s) {
    const short* src = wpack + (((size_t)s * NCOL + n0) << 6) + (tid << 3);
    short* ldst = bdst + (w << 9);      // wave-uniform base; HW adds lane*16B
    #pragma unroll
    for (int rnd = 0; rnd < 8; ++rnd)
      gload_lds16(src + rnd * 2048, ldst + rnd * 2048);
  };

  // per-lane x for this step: x[row] for the wave's 4 row-tiles (broadcast across q)
  float xrc[4], xic[4];
  auto load_x = [&](int s, float* xr, float* xi) {
    #pragma unroll
    for (int mm = 0; mm < 4; ++mm) {
      int row = b0 + wr * 64 + mm * 16 + lm;
      xr[mm] = __half2float(xTre[(size_t)s * B_SZ + row]);
      xi[mm] = __half2float(xTim[(size_t)s * B_SZ + row]);
    }
  };

  // ---- prologue ----
  {
    int s0 = kch * 32;
    load_x(s0, xrc, xic);
    stage_B(&Bs[0][0], s0);
    asm volatile("s_waitcnt vmcnt(0) lgkmcnt(0)" ::: "memory");
  }
  __syncthreads();

  for (int t = 0; t < 33; ++t) {
    const bool last = (t == 32);        // silu step
    // prefetch next-step x; stage next B tile (drains at this step's end, fully covered)
    float xrn[4], xin[4];
    if (t < 31) load_x(kch * 32 + t + 1, xrn, xin);
    if (t < 32) stage_B(&Bs[(t + 1) & 1][0], (t + 1 < 32) ? (kch * 32 + t + 1) : (256 + kch));
    __builtin_amdgcn_sched_barrier(0);  // keep the issues above the compute below

    const short* bb = &Bs[t & 1][0];

    // ---- lo half (k-group u = q): B frags (R0-verified swizzled read), A in-reg, 32 MFMA ----
    short8 bf[8];
    #pragma unroll
    for (int nn = 0; nn < 8; ++nn) {
      int colL = wc * 128 + nn * 16 + lm;
      bf[nn] = *(const short8*)(bb + (colL << 6) + ((q ^ (colL & 7)) << 3));
    }
    short8 afh[4];                      // hi-half A frags, built alongside (eiv shared)
    #pragma unroll
    for (int mm = 0; mm < 4; ++mm) {
      short8 alo;
      if (!last) {
        float eiv[8];
        #pragma unroll
        for (int v = 0; v < 8; ++v) {
          float d = xic[mm] - (-2.0f + v * GSTEP);
          eiv[v] = __builtin_amdgcn_exp2f(d * d * NLOG2E);
        }
        float d0 = xrc[mm] - gq;
        float er = __builtin_amdgcn_exp2f(d0 * d0 * NLOG2E);
        float d1 = xrc[mm] - gq4;
        float e4 = __builtin_amdgcn_exp2f(d1 * d1 * NLOG2E);
        uint4 va = make_uint4(pk_bf16(er * eiv[0], er * eiv[1]), pk_bf16(er * eiv[2], er * eiv[3]),
                              pk_bf16(er * eiv[4], er * eiv[5]), pk_bf16(er * eiv[6], er * eiv[7]));
        uint4 vh = make_uint4(pk_bf16(e4 * eiv[0], e4 * eiv[1]), pk_bf16(e4 * eiv[2], e4 * eiv[3]),
                              pk_bf16(e4 * eiv[4], e4 * eiv[5]), pk_bf16(e4 * eiv[6], e4 * eiv[7]));
        alo = *(short8*)&va; afh[mm] = *(short8*)&vh;
      } else {
        // silu step: A[row][k=u*8+e] = silu(x_{e&1}[row][kch*32 + u*4 + (e>>1)])
        int row = b0 + wr * 64 + mm * 16 + lm;
        const float* pr = xre + (size_t)row * I_SZ + (kch << 5);
        const float* pi = xim + (size_t)row * I_SZ + (kch << 5);
        uint4 va = make_uint4(pk_bf16(silu_f(pr[q * 4 + 0]), silu_f(pi[q * 4 + 0])),
                              pk_bf16(silu_f(pr[q * 4 + 1]), silu_f(pi[q * 4 + 1])),
                              pk_bf16(silu_f(pr[q * 4 + 2]), silu_f(pi[q * 4 + 2])),
                              pk_bf16(silu_f(pr[q * 4 + 3]), silu_f(pi[q * 4 + 3])));
        uint4 vh = make_uint4(pk_bf16(silu_f(pr[q * 4 + 16]), silu_f(pi[q * 4 + 16])),
                              pk_bf16(silu_f(pr[q * 4 + 17]), silu_f(pi[q * 4 + 17])),
                              pk_bf16(silu_f(pr[q * 4 + 18]), silu_f(pi[q * 4 + 18])),
                              pk_bf16(silu_f(pr[q * 4 + 19]), silu_f(pi[q * 4 + 19])));
        alo = *(short8*)&va; afh[mm] = *(short8*)&vh;
      }
      __builtin_amdgcn_s_setprio(1);
      #pragma unroll
      for (int nn = 0; nn < 8; ++nn)
        acc[mm][nn] = __builtin_amdgcn_mfma_f32_16x16x32_bf16(alo, bf[nn], acc[mm][nn], 0, 0, 0);
      __builtin_amdgcn_s_setprio(0);
    }

    // ---- hi half (k-group u = q+4): re-read B frags, MFMA with stored afh ----
    #pragma unroll
    for (int nn = 0; nn < 8; ++nn) {
      int colL = wc * 128 + nn * 16 + lm;
      bf[nn] = *(const short8*)(bb + (colL << 6) + (((q + 4) ^ (colL & 7)) << 3));
    }
    __builtin_amdgcn_s_setprio(1);
    #pragma unroll
    for (int mm = 0; mm < 4; ++mm)
      #pragma unroll
      for (int nn = 0; nn < 8; ++nn)
        acc[mm][nn] = __builtin_amdgcn_mfma_f32_16x16x32_bf16(afh[mm], bf[nn], acc[mm][nn], 0, 0, 0);
    __builtin_amdgcn_s_setprio(0);

    if (t < 31) {
      #pragma unroll
      for (int mm = 0; mm < 4; ++mm) { xrc[mm] = xrn[mm]; xic[mm] = xin[mm]; }
    }
    if (t < 32) {
      // own stage loads were issued a full step of compute ago -> near-zero wait
      asm volatile("s_waitcnt vmcnt(0) lgkmcnt(0)" ::: "memory");
      __syncthreads();
    }
  }

  // ---- epilogue: C/D layout col=lane&15, row=q*4+reg; bias added by chunk-7 only ----
  #pragma unroll
  for (int nn = 0; nn < 8; ++nn) {
    int col = n0 + wc * 128 + nn * 16 + lm;
    float bv = (kch == 7) ? bsum[col] : 0.0f;
    #pragma unroll
    for (int mm = 0; mm < 4; ++mm) {
      int row0 = b0 + wr * 64 + mm * 16 + (q << 2);
      #pragma unroll
      for (int r2 = 0; r2 < 4; ++r2)
        atomicAdd(out + (size_t)(row0 + r2) * NCOL + col, acc[mm][nn][r2] + bv);
    }
  }
}

extern "C" void kernel_launch(void* const* d_in, const int* in_sizes, int n_in,
                              void* d_out, int out_size, void* d_ws, size_t ws_size,
                              hipStream_t stream) {
  const float* xre  = (const float*)d_in[0];
  const float* xim  = (const float*)d_in[1];
  const float* rw   = (const float*)d_in[2];
  const float* cw   = (const float*)d_in[3];
  const float* swre = (const float*)d_in[4];
  const float* swim = (const float*)d_in[5];
  const float* bre  = (const float*)d_in[6];
  const float* bim  = (const float*)d_in[7];
  float* out = (float*)d_out;

  size_t wpack_bytes = (size_t)KSTEPS * NCOL * 64 * 2;   // 16.5 MiB
  short* wpack = (short*)d_ws;
  float* bsum  = (float*)((char*)d_ws + wpack_bytes);
  __half* xT   = (__half*)((char*)d_ws + wpack_bytes + 2048);  // 2 planes * 256*4096 fp16

  hipMemsetAsync(d_out, 0, (size_t)B_SZ * NCOL * sizeof(float), stream);
  pack_weights<<<(KSTEPS * NCOL * 8) / 256, 256, 0, stream>>>(rw, cw, swre, swim, wpack);
  transpose_x<<<512, 256, 0, stream>>>(xre, xim, xT);
  bias_sums<<<NCOL, 64, 0, stream>>>(bre, bim, bsum);
  cvkan_gemm<<<512, 256, 0, stream>>>(xre, xim, xT, wpack, bsum, out);
}